// Round 3
// baseline (79.391 us; speedup 1.0000x reference)
//
#include <hip/hip_runtime.h>
#include <hip/hip_bf16.h>
#include <stdint.h>

#define DIM 1024
#define BATCH 128
#define EPS_BN 1e-5f
#define KSPLIT 4
#define NBLOCKS 768   // 4(mt) x 48(nt) x 4(ks); 3 blocks/CU on 256 CUs

typedef __attribute__((ext_vector_type(8))) short bfrag;   // 8 bf16 (4 VGPRs)
typedef __attribute__((ext_vector_type(4))) float f32x4;   // MFMA accumulator

__device__ inline ushort f2bf(float f) {
    union { __hip_bfloat16 h; ushort u; } c;
    c.h = __float2bfloat16(f);   // RNE; pairs into v_cvt_pk_bf16_f32
    return c.u;
}

__device__ inline void cvt8(float4 f0, float4 f1, ushort* o) {
    o[0] = f2bf(f0.x); o[1] = f2bf(f0.y); o[2] = f2bf(f0.z); o[3] = f2bf(f0.w);
    o[4] = f2bf(f1.x); o[5] = f2bf(f1.y); o[6] = f2bf(f1.z); o[7] = f2bf(f1.w);
}

// capped acquire-spin: never hangs even if co-residency were violated
__device__ inline void spin_until(int* p, int target) {
    for (int i = 0; i < (1 << 21); ++i) {
        if (__hip_atomic_load(p, __ATOMIC_ACQUIRE, __HIP_MEMORY_SCOPE_AGENT) >= target)
            return;
        __builtin_amdgcn_s_sleep(2);
    }
}

// ---------------------------------------------------------------------------
// One kernel, three phases separated by device-scope grid barriers.
// Phase 1 (768 blocks): split-K GEMM, BM=32 BN=64, K-range 256 each.
//   All 24 float4 global loads issued up-front (latency paid once), then
//   4 iters of {cvt->LDS dbuf, 1 barrier, 4 MFMA}.
// Phase 2 (blocks 0..127): combine K-partials + Taylor-moment attention.
// Phase 3 (blocks 0..31): BatchNorm over batch axis.
// ---------------------------------------------------------------------------
__global__ __launch_bounds__(256, 3) void fused_all(
    const float* __restrict__ z, const float* __restrict__ Wq,
    const float* __restrict__ Wk, const float* __restrict__ Wv,
    const float* __restrict__ gamma, const float* __restrict__ beta,
    float* __restrict__ qkvp, float* __restrict__ out0,
    float* __restrict__ out, int* __restrict__ sync)
{
    __shared__ alignas(16) ushort As[2][32][72];   // +8 pad: breaks bank cycling
    __shared__ alignas(16) ushort Bs[2][64][72];
    __shared__ float red0[4][9], red1[4][9];
    __shared__ float ls[8][32], ls2[8][32], la[32], lb[32];

    const int bid = blockIdx.x;
    const int t = threadIdx.x;
    const int lane = t & 63, wvi = t >> 6;
    const int wm = wvi >> 1, wn = wvi & 1;
    const size_t BD = (size_t)BATCH * DIM;

    // ================= Phase 1: GEMM =================
    {
        const int ks = bid & 3;
        const int bid2 = bid >> 2;
        const int nt = bid2 % 48, mt = bid2 / 48;
        const int m0 = mt * 32;
        const int n0 = nt * 64;
        const int w_idx = n0 >> 10;
        const float* W = (w_idx == 0) ? Wq : (w_idx == 1) ? Wk : Wv;
        const int nrow0 = n0 & 1023;
        const int k0 = ks * 256;

        const int ar = t >> 3, ac = (t & 7) * 8;    // A tile [32][64]
        const int br = t >> 2, bc = (t & 3) * 16;   // B tile [64][64]
        const float* zrow = z + (size_t)(m0 + ar) * DIM + k0 + ac;
        const float* wrow = W + (size_t)(nrow0 + br) * DIM + k0 + bc;

        // issue ALL global loads up-front: max memory-level parallelism
        float4 Ab[4][2], Bb[4][4];
        #pragma unroll
        for (int i = 0; i < 4; ++i) {
            Ab[i][0] = *(const float4*)(zrow + i * 64);
            Ab[i][1] = *(const float4*)(zrow + i * 64 + 4);
            Bb[i][0] = *(const float4*)(wrow + i * 64);
            Bb[i][1] = *(const float4*)(wrow + i * 64 + 4);
            Bb[i][2] = *(const float4*)(wrow + i * 64 + 8);
            Bb[i][3] = *(const float4*)(wrow + i * 64 + 12);
        }

        f32x4 acc[2] = {{0.f,0.f,0.f,0.f},{0.f,0.f,0.f,0.f}};

        #pragma unroll
        for (int i = 0; i < 4; ++i) {
            const int pb = i & 1;
            {
                ushort ta[8];
                cvt8(Ab[i][0], Ab[i][1], ta);
                *(bfrag*)&As[pb][ar][ac] = *(bfrag*)ta;
                ushort tb[16];
                cvt8(Bb[i][0], Bb[i][1], tb);
                cvt8(Bb[i][2], Bb[i][3], tb + 8);
                *(bfrag*)&Bs[pb][br][bc]     = *(bfrag*)tb;
                *(bfrag*)&Bs[pb][br][bc + 8] = *(bfrag*)(tb + 8);
            }
            __syncthreads();
            // write(i+1) goes to the OTHER buffer; one barrier per iter is safe
            const int krow = (lane >> 4) * 8;
            #pragma unroll
            for (int mk = 0; mk < 2; ++mk) {
                bfrag af  = *(const bfrag*)&As[pb][wm * 16      + (lane & 15)][mk * 32 + krow];
                bfrag bf0 = *(const bfrag*)&Bs[pb][wn * 32      + (lane & 15)][mk * 32 + krow];
                bfrag bf1 = *(const bfrag*)&Bs[pb][wn * 32 + 16 + (lane & 15)][mk * 32 + krow];
                acc[0] = __builtin_amdgcn_mfma_f32_16x16x32_bf16(af, bf0, acc[0], 0, 0, 0);
                acc[1] = __builtin_amdgcn_mfma_f32_16x16x32_bf16(af, bf1, acc[1], 0, 0, 0);
            }
        }

        // epilogue: C/D layout: col = lane&15, row = (lane>>4)*4 + reg
        float* outbase = qkvp + (size_t)ks * (3 * BD) + (size_t)w_idx * BD;
        #pragma unroll
        for (int fn = 0; fn < 2; ++fn) {
            const int col = nrow0 + wn * 32 + fn * 16 + (lane & 15);
            #pragma unroll
            for (int r = 0; r < 4; ++r) {
                const int row = m0 + wm * 16 + (lane >> 4) * 4 + r;
                outbase[(size_t)row * DIM + col] = acc[fn][r];
            }
        }
    }

    // ---- grid barrier 1 (768 blocks, all co-resident by launch_bounds) ----
    __syncthreads();   // drains vmcnt: epilogue stores reached L2
    if (t == 0) __hip_atomic_fetch_add(&sync[0], 1, __ATOMIC_RELEASE,
                                       __HIP_MEMORY_SCOPE_AGENT);
    if (bid >= BATCH) return;
    if (t == 0) spin_until(&sync[0], NBLOCKS);
    __syncthreads();

    // ================= Phase 2: attention (Taylor moments) =================
    const int b = bid;
    const float inv_n = 0.03125f;  // 1/sqrt(1024)

    float qv[4], kn[4], vv[4];
    #pragma unroll
    for (int c = 0; c < 4; ++c) {
        const int j = t + c * 256;
        float qs = 0.f, kks = 0.f, vs = 0.f;
        #pragma unroll
        for (int p = 0; p < KSPLIT; ++p) {
            const float* base = qkvp + (size_t)p * 3 * BD + (size_t)b * DIM + j;
            qs  += base[0];
            kks += base[BD];
            vs  += base[2 * BD];
        }
        qv[c] = qs; kn[c] = kks * inv_n; vv[c] = vs;
    }

    float m0p[9], m1p[9];
    #pragma unroll
    for (int p = 0; p < 9; ++p) { m0p[p] = 0.f; m1p[p] = 0.f; }
    #pragma unroll
    for (int c = 0; c < 4; ++c) {
        float pw = 1.f;
        #pragma unroll
        for (int p = 0; p < 9; ++p) { m0p[p] += pw; m1p[p] += pw * vv[c]; pw *= kn[c]; }
    }
    #pragma unroll
    for (int p = 0; p < 9; ++p) {
        for (int off = 32; off; off >>= 1) {
            m0p[p] += __shfl_xor(m0p[p], off);
            m1p[p] += __shfl_xor(m1p[p], off);
        }
    }
    if (lane == 0) {
        #pragma unroll
        for (int p = 0; p < 9; ++p) { red0[wvi][p] = m0p[p]; red1[wvi][p] = m1p[p]; }
    }
    __syncthreads();

    const float invfact[9] = {1.f, 1.f, 0.5f, 1.f/6.f, 1.f/24.f, 1.f/120.f,
                              1.f/720.f, 1.f/5040.f, 1.f/40320.f};
    float c0[9], c1[9];
    #pragma unroll
    for (int p = 0; p < 9; ++p) {
        const float s0 = red0[0][p] + red0[1][p] + red0[2][p] + red0[3][p];
        const float s1 = red1[0][p] + red1[1][p] + red1[2][p] + red1[3][p];
        c0[p] = s0 * invfact[p];
        c1[p] = s1 * invfact[p];
    }
    #pragma unroll
    for (int c = 0; c < 4; ++c) {
        const float qi = qv[c];
        float S = c0[8], N = c1[8];
        #pragma unroll
        for (int p = 7; p >= 0; --p) { S = S * qi + c0[p]; N = N * qi + c1[p]; }
        out0[(size_t)b * DIM + t + c * 256] = N / S + vv[c];
    }

    // ---- grid barrier 2 (128 blocks) ----
    __syncthreads();
    if (t == 0) __hip_atomic_fetch_add(&sync[1], 1, __ATOMIC_RELEASE,
                                       __HIP_MEMORY_SCOPE_AGENT);
    if (bid >= 32) return;
    if (t == 0) spin_until(&sync[1], BATCH);
    __syncthreads();

    // ================= Phase 3: BatchNorm =================
    const int f = bid * 32 + (t & 31);
    const int rc = t >> 5;  // 0..7, each covers 16 batch rows

    float x[16];
    float s = 0.f, s2 = 0.f;
    #pragma unroll
    for (int it = 0; it < 16; ++it) {
        const float xx = out0[(size_t)(rc * 16 + it) * DIM + f];
        x[it] = xx; s += xx; s2 += xx * xx;
    }
    ls[rc][t & 31] = s; ls2[rc][t & 31] = s2;
    __syncthreads();
    if (rc == 0) {
        float ss = 0.f, ss2 = 0.f;
        #pragma unroll
        for (int r = 0; r < 8; ++r) { ss += ls[r][t]; ss2 += ls2[r][t]; }
        const float mean = ss * (1.f / 128.f);
        const float var = ss2 * (1.f / 128.f) - mean * mean;  // biased
        const float inv = rsqrtf(var + EPS_BN);
        const float a = gamma[f] * inv;
        la[t] = a; lb[t] = beta[f] - mean * a;
    }
    __syncthreads();
    const float a = la[t & 31], bb = lb[t & 31];
    #pragma unroll
    for (int it = 0; it < 16; ++it) {
        out[(size_t)(rc * 16 + it) * DIM + f] = x[it] * a + bb;
    }
}

// ---------------------------------------------------------------------------
extern "C" void kernel_launch(void* const* d_in, const int* in_sizes, int n_in,
                              void* d_out, int out_size, void* d_ws, size_t ws_size,
                              hipStream_t stream)
{
    const float* z     = (const float*)d_in[0];
    const float* Wq    = (const float*)d_in[1];
    const float* Wk    = (const float*)d_in[2];
    const float* Wv    = (const float*)d_in[3];
    const float* gamma = (const float*)d_in[4];
    const float* beta  = (const float*)d_in[5];
    float* out = (float*)d_out;

    float* qkvp = (float*)d_ws;                              // 4 x 3 x 128 x 1024 f32
    float* out0 = qkvp + (size_t)KSPLIT * 3 * BATCH * DIM;   // 128 x 1024 f32
    int*   sync = (int*)(out0 + (size_t)BATCH * DIM);        // 2 barrier counters

    hipMemsetAsync(sync, 0, 2 * sizeof(int), stream);        // capture-safe
    fused_all<<<NBLOCKS, 256, 0, stream>>>(z, Wq, Wk, Wv, gamma, beta,
                                           qkvp, out0, out, sync);
}

// Round 4
// 26.814 us; speedup vs baseline: 2.9608x; 2.9608x over previous
//
#include <hip/hip_runtime.h>
#include <hip/hip_bf16.h>
#include <stdint.h>

#define DIM 1024
#define BATCH 128
#define EPS_BN 1e-5f
#define KSPLIT 4

typedef __attribute__((ext_vector_type(8))) short bfrag;   // 8 bf16 (4 VGPRs)
typedef __attribute__((ext_vector_type(4))) float f32x4;   // MFMA accumulator

__device__ inline ushort f2bf(float f) {
    union { __hip_bfloat16 h; ushort u; } c;
    c.h = __float2bfloat16(f);   // RNE; pairs into v_cvt_pk_bf16_f32
    return c.u;
}

// capped acquire-spin: never hangs even if co-residency were violated
__device__ inline void spin_until(int* p, int target) {
    for (int i = 0; i < (1 << 21); ++i) {
        if (__hip_atomic_load(p, __ATOMIC_ACQUIRE, __HIP_MEMORY_SCOPE_AGENT) >= target)
            return;
        __builtin_amdgcn_s_sleep(2);
    }
}

// ---------------------------------------------------------------------------
// K1: q,k,v = z @ W.T (three 128x1024x1024 GEMMs, N=3072), split-K=4.
// Tile BM=32, BN=64, K-range 256 staged in ONE shot -> ONE barrier per block.
// Grid = 4(mt) x 48(nt) x 4(ks) = 768 blocks -> 3 blocks/CU (LDS ~50KB).
// ---------------------------------------------------------------------------
__global__ void qkv_gemm(
    const float* __restrict__ z, const float* __restrict__ Wq,
    const float* __restrict__ Wk, const float* __restrict__ Wv,
    float* __restrict__ qkvp)
{
    // row stride 264 bf16 = 528B: rows land on rotating banks (2-way max = free)
    __shared__ alignas(16) ushort As[32][264];
    __shared__ alignas(16) ushort Bs[64][264];

    const int bid = blockIdx.x;
    const int ks = bid & 3;
    const int bid2 = bid >> 2;
    const int nt = bid2 % 48, mt = bid2 / 48;
    const int m0 = mt * 32;
    const int n0 = nt * 64;
    const int w_idx = n0 >> 10;                 // which W (tile never crosses)
    const float* W = (w_idx == 0) ? Wq : (w_idx == 1) ? Wk : Wv;
    const int nrow0 = n0 & 1023;
    const int k0 = ks * 256;

    const int t = threadIdx.x;
    const int lane = t & 63, wvi = t >> 6;
    const int wm = wvi >> 1, wn = wvi & 1;
    const size_t BD = (size_t)BATCH * DIM;

    // ---- stage A: 32x256 f32 -> bf16. 1024 pairs-of-float4; 4 per thread ----
    #pragma unroll
    for (int g = 0; g < 4; ++g) {
        const int p = t + 256 * g;
        const int row = p >> 5, c8 = (p & 31) * 8;
        const float* src = z + (size_t)(m0 + row) * DIM + k0 + c8;
        float4 f0 = *(const float4*)src;
        float4 f1 = *(const float4*)(src + 4);
        ushort tmp[8] = { f2bf(f0.x), f2bf(f0.y), f2bf(f0.z), f2bf(f0.w),
                          f2bf(f1.x), f2bf(f1.y), f2bf(f1.z), f2bf(f1.w) };
        *(bfrag*)&As[row][c8] = *(bfrag*)tmp;
    }
    // ---- stage B: 64x256 f32 -> bf16. 2048 pairs; 8 per thread ----
    #pragma unroll
    for (int g = 0; g < 8; ++g) {
        const int p = t + 256 * g;
        const int row = p >> 5, c8 = (p & 31) * 8;
        const float* src = W + (size_t)(nrow0 + row) * DIM + k0 + c8;
        float4 f0 = *(const float4*)src;
        float4 f1 = *(const float4*)(src + 4);
        ushort tmp[8] = { f2bf(f0.x), f2bf(f0.y), f2bf(f0.z), f2bf(f0.w),
                          f2bf(f1.x), f2bf(f1.y), f2bf(f1.z), f2bf(f1.w) };
        *(bfrag*)&Bs[row][c8] = *(bfrag*)tmp;
    }
    __syncthreads();   // the ONLY barrier

    // ---- MFMA phase: 8 k-steps of K=32 ----
    const int l15 = lane & 15;
    const int kr8 = (lane >> 4) * 8;   // lane-group K slot (same bijection A & B)
    f32x4 acc[2] = {{0.f,0.f,0.f,0.f},{0.f,0.f,0.f,0.f}};
    #pragma unroll
    for (int s = 0; s < 8; ++s) {
        bfrag af  = *(const bfrag*)&As[wm * 16      + l15][s * 32 + kr8];
        bfrag bf0 = *(const bfrag*)&Bs[wn * 32      + l15][s * 32 + kr8];
        bfrag bf1 = *(const bfrag*)&Bs[wn * 32 + 16 + l15][s * 32 + kr8];
        acc[0] = __builtin_amdgcn_mfma_f32_16x16x32_bf16(af, bf0, acc[0], 0, 0, 0);
        acc[1] = __builtin_amdgcn_mfma_f32_16x16x32_bf16(af, bf1, acc[1], 0, 0, 0);
    }

    // epilogue: C/D layout: col = lane&15, row = (lane>>4)*4 + reg
    float* outbase = qkvp + (size_t)ks * (3 * BD) + (size_t)w_idx * BD;
    #pragma unroll
    for (int fn = 0; fn < 2; ++fn) {
        const int col = nrow0 + wn * 32 + fn * 16 + l15;
        #pragma unroll
        for (int r = 0; r < 4; ++r) {
            const int row = m0 + wm * 16 + (lane >> 4) * 4 + r;
            outbase[(size_t)row * DIM + col] = acc[fn][r];
        }
    }
}

// ---------------------------------------------------------------------------
// K2 (fused, proven in round 2): combine K-partials, Taylor-moment attention,
// 128-wide grid barrier, BatchNorm tail on blocks 0..31.
// ---------------------------------------------------------------------------
__global__ __launch_bounds__(256) void attn_bn(
    const float* __restrict__ qkvp, const float* __restrict__ gamma,
    const float* __restrict__ beta, float* __restrict__ out0,
    float* __restrict__ out, int* __restrict__ sync)
{
    const int b = blockIdx.x;
    const int t = threadIdx.x;
    const size_t BD = (size_t)BATCH * DIM;
    const float inv_n = 0.03125f;  // 1/sqrt(1024)

    // combine split-K partials
    float qv[4], kn[4], vv[4];
    #pragma unroll
    for (int c = 0; c < 4; ++c) {
        const int j = t + c * 256;
        float qs = 0.f, kks = 0.f, vs = 0.f;
        #pragma unroll
        for (int p = 0; p < KSPLIT; ++p) {
            const float* base = qkvp + (size_t)p * 3 * BD + (size_t)b * DIM + j;
            qs  += base[0];
            kks += base[BD];
            vs  += base[2 * BD];
        }
        qv[c] = qs; kn[c] = kks * inv_n; vv[c] = vs;
    }

    float m0p[9], m1p[9];
    #pragma unroll
    for (int p = 0; p < 9; ++p) { m0p[p] = 0.f; m1p[p] = 0.f; }
    #pragma unroll
    for (int c = 0; c < 4; ++c) {
        float pw = 1.f;
        #pragma unroll
        for (int p = 0; p < 9; ++p) { m0p[p] += pw; m1p[p] += pw * vv[c]; pw *= kn[c]; }
    }
    #pragma unroll
    for (int p = 0; p < 9; ++p) {
        for (int off = 32; off; off >>= 1) {
            m0p[p] += __shfl_xor(m0p[p], off);
            m1p[p] += __shfl_xor(m1p[p], off);
        }
    }
    __shared__ float red0[4][9], red1[4][9];
    const int wvi = t >> 6, lane = t & 63;
    if (lane == 0) {
        #pragma unroll
        for (int p = 0; p < 9; ++p) { red0[wvi][p] = m0p[p]; red1[wvi][p] = m1p[p]; }
    }
    __syncthreads();

    const float invfact[9] = {1.f, 1.f, 0.5f, 1.f/6.f, 1.f/24.f, 1.f/120.f,
                              1.f/720.f, 1.f/5040.f, 1.f/40320.f};
    float c0[9], c1[9];
    #pragma unroll
    for (int p = 0; p < 9; ++p) {
        const float s0 = red0[0][p] + red0[1][p] + red0[2][p] + red0[3][p];
        const float s1 = red1[0][p] + red1[1][p] + red1[2][p] + red1[3][p];
        c0[p] = s0 * invfact[p];
        c1[p] = s1 * invfact[p];
    }
    #pragma unroll
    for (int c = 0; c < 4; ++c) {
        const float qi = qv[c];
        float S = c0[8], N = c1[8];
        #pragma unroll
        for (int p = 7; p >= 0; --p) { S = S * qi + c0[p]; N = N * qi + c1[p]; }
        out0[(size_t)b * DIM + t + c * 256] = N / S + vv[c];
    }

    // ---- grid barrier (128 blocks; proven benign in round 2) ----
    __syncthreads();   // drains vmcnt -> stores reached L2
    if (t == 0) __hip_atomic_fetch_add(sync, 1, __ATOMIC_RELEASE,
                                       __HIP_MEMORY_SCOPE_AGENT);
    if (b >= 32) return;
    if (t == 0) spin_until(sync, BATCH);
    __syncthreads();

    // ---- BatchNorm tail: block b handles features b*32 .. b*32+31 ----
    __shared__ float ls[8][32], ls2[8][32], la[32], lb[32];
    const int f = b * 32 + (t & 31);
    const int rc = t >> 5;  // 0..7, each covers 16 batch rows

    float x[16];
    float s = 0.f, s2 = 0.f;
    #pragma unroll
    for (int it = 0; it < 16; ++it) {
        const float xx = out0[(size_t)(rc * 16 + it) * DIM + f];
        x[it] = xx; s += xx; s2 += xx * xx;
    }
    ls[rc][t & 31] = s; ls2[rc][t & 31] = s2;
    __syncthreads();
    if (rc == 0) {
        float ss = 0.f, ss2 = 0.f;
        #pragma unroll
        for (int r = 0; r < 8; ++r) { ss += ls[r][t]; ss2 += ls2[r][t]; }
        const float mean = ss * (1.f / 128.f);
        const float var = ss2 * (1.f / 128.f) - mean * mean;  // biased
        const float inv = rsqrtf(var + EPS_BN);
        const float a = gamma[f] * inv;
        la[t] = a; lb[t] = beta[f] - mean * a;
    }
    __syncthreads();
    const float a = la[t & 31], bb = lb[t & 31];
    #pragma unroll
    for (int it = 0; it < 16; ++it) {
        out[(size_t)(rc * 16 + it) * DIM + f] = x[it] * a + bb;
    }
}

// ---------------------------------------------------------------------------
extern "C" void kernel_launch(void* const* d_in, const int* in_sizes, int n_in,
                              void* d_out, int out_size, void* d_ws, size_t ws_size,
                              hipStream_t stream)
{
    const float* z     = (const float*)d_in[0];
    const float* Wq    = (const float*)d_in[1];
    const float* Wk    = (const float*)d_in[2];
    const float* Wv    = (const float*)d_in[3];
    const float* gamma = (const float*)d_in[4];
    const float* beta  = (const float*)d_in[5];
    float* out = (float*)d_out;

    float* qkvp = (float*)d_ws;                              // 4 x 3 x 128 x 1024 f32
    float* out0 = qkvp + (size_t)KSPLIT * 3 * BATCH * DIM;   // 128 x 1024 f32
    int*   sync = (int*)(out0 + (size_t)BATCH * DIM);        // barrier counter

    hipMemsetAsync(sync, 0, 2 * sizeof(int), stream);        // capture-safe
    qkv_gemm<<<4 * 48 * KSPLIT, 256, 0, stream>>>(z, Wq, Wk, Wv, qkvp);
    attn_bn<<<BATCH, 256, 0, stream>>>(qkvp, gamma, beta, out0, out, sync);
}

// Round 5
// 24.256 us; speedup vs baseline: 3.2731x; 1.1055x over previous
//
#include <hip/hip_runtime.h>
#include <hip/hip_bf16.h>
#include <stdint.h>

#define DIM 1024
#define BATCH 128
#define EPS_BN 1e-5f
#define KSPLIT 4

typedef __attribute__((ext_vector_type(8))) short bfrag;   // 8 bf16 (4 VGPRs)
typedef __attribute__((ext_vector_type(4))) float f32x4;   // MFMA accumulator

__device__ inline ushort f2bf(float f) {
    union { __hip_bfloat16 h; ushort u; } c;
    c.h = __float2bfloat16(f);   // RNE; pairs into v_cvt_pk_bf16_f32
    return c.u;
}

__device__ inline void cvt8(float4 f0, float4 f1, ushort* o) {
    o[0] = f2bf(f0.x); o[1] = f2bf(f0.y); o[2] = f2bf(f0.z); o[3] = f2bf(f0.w);
    o[4] = f2bf(f1.x); o[5] = f2bf(f1.y); o[6] = f2bf(f1.z); o[7] = f2bf(f1.w);
}

// capped acquire-spin: never hangs even if co-residency were violated
__device__ inline void spin_until(int* p, int target) {
    for (int i = 0; i < (1 << 21); ++i) {
        if (__hip_atomic_load(p, __ATOMIC_ACQUIRE, __HIP_MEMORY_SCOPE_AGENT) >= target)
            return;
        __builtin_amdgcn_s_sleep(2);
    }
}

struct LoadSet { float4 a0, a1, b0, b1, b2, b3; };

__device__ inline void issue_loads(const float* zp, const float* wp, int off,
                                   LoadSet& s) {
    s.a0 = *(const float4*)(zp + off);
    s.a1 = *(const float4*)(zp + off + 4);
    s.b0 = *(const float4*)(wp + off);
    s.b1 = *(const float4*)(wp + off + 4);
    s.b2 = *(const float4*)(wp + off + 8);
    s.b3 = *(const float4*)(wp + off + 12);
}

__device__ inline void stage(const LoadSet& s,
                             ushort (*As)[72], ushort (*Bs)[72],
                             int ar, int ac, int br, int bc) {
    ushort ta[8]; cvt8(s.a0, s.a1, ta); *(bfrag*)&As[ar][ac] = *(bfrag*)ta;
    ushort tb[8]; cvt8(s.b0, s.b1, tb); *(bfrag*)&Bs[br][bc] = *(bfrag*)tb;
    ushort tc[8]; cvt8(s.b2, s.b3, tc); *(bfrag*)&Bs[br][bc + 8] = *(bfrag*)tc;
}

__device__ inline void do_mfma(const ushort (*As)[72], const ushort (*Bs)[72],
                               int wm, int wn, int l15, int kr8, f32x4* acc) {
    #pragma unroll
    for (int mk = 0; mk < 2; ++mk) {
        bfrag af  = *(const bfrag*)&As[wm * 16      + l15][mk * 32 + kr8];
        bfrag bf0 = *(const bfrag*)&Bs[wn * 32      + l15][mk * 32 + kr8];
        bfrag bf1 = *(const bfrag*)&Bs[wn * 32 + 16 + l15][mk * 32 + kr8];
        acc[0] = __builtin_amdgcn_mfma_f32_16x16x32_bf16(af, bf0, acc[0], 0, 0, 0);
        acc[1] = __builtin_amdgcn_mfma_f32_16x16x32_bf16(af, bf1, acc[1], 0, 0, 0);
    }
}

// ---------------------------------------------------------------------------
// K1: q,k,v = z @ W.T (M=128, K=1024, N=3072), split-K=4.
// BM=32, BN=64, BK=64, 4 K-iters. Software-pipelined: next iter's 6 float4
// prefetched in regs while current iter cvt/ds_write/MFMAs; LDS dbuf ->
// ONE barrier per iter. Grid 768 = 3 blocks/CU. Also zeroes the grid-barrier
// counter used by attn_bn (saves a memset dispatch).
// ---------------------------------------------------------------------------
__global__ __launch_bounds__(256) void qkv_gemm(
    const float* __restrict__ z, const float* __restrict__ Wq,
    const float* __restrict__ Wk, const float* __restrict__ Wv,
    float* __restrict__ qkvp, int* __restrict__ sync)
{
    if (blockIdx.x == 0 && threadIdx.x == 0) { sync[0] = 0; sync[1] = 0; }

    __shared__ alignas(16) ushort As[2][32][72];
    __shared__ alignas(16) ushort Bs[2][64][72];

    const int bid = blockIdx.x;
    const int ks = bid & 3;
    const int bid2 = bid >> 2;
    const int nt = bid2 % 48, mt = bid2 / 48;
    const int m0 = mt * 32;
    const int n0 = nt * 64;
    const int w_idx = n0 >> 10;                 // which W (tile never crosses)
    const float* W = (w_idx == 0) ? Wq : (w_idx == 1) ? Wk : Wv;
    const int nrow0 = n0 & 1023;
    const int k0 = ks * 256;

    const int t = threadIdx.x;
    const int lane = t & 63, wvi = t >> 6;
    const int wm = wvi >> 1, wn = wvi & 1;
    const int l15 = lane & 15, kr8 = (lane >> 4) * 8;
    const size_t BD = (size_t)BATCH * DIM;

    const int ar = t >> 3, ac = (t & 7) * 8;    // A tile [32][64]
    const int br = t >> 2, bc = (t & 3) * 16;   // B tile [64][64]
    const float* zrow = z + (size_t)(m0 + ar) * DIM + k0 + ac;
    const float* wrow = W + (size_t)(nrow0 + br) * DIM + k0 + bc;

    f32x4 acc[2] = {{0.f,0.f,0.f,0.f},{0.f,0.f,0.f,0.f}};
    LoadSet s0, s1;

    // pipelined 4-iter K loop, hand-unrolled to alternate reg sets & LDS bufs
    issue_loads(zrow, wrow, 0, s0);

    issue_loads(zrow, wrow, 64, s1);
    stage(s0, As[0], Bs[0], ar, ac, br, bc);
    __syncthreads();
    do_mfma(As[0], Bs[0], wm, wn, l15, kr8, acc);

    issue_loads(zrow, wrow, 128, s0);
    stage(s1, As[1], Bs[1], ar, ac, br, bc);
    __syncthreads();
    do_mfma(As[1], Bs[1], wm, wn, l15, kr8, acc);

    issue_loads(zrow, wrow, 192, s1);
    stage(s0, As[0], Bs[0], ar, ac, br, bc);
    __syncthreads();
    do_mfma(As[0], Bs[0], wm, wn, l15, kr8, acc);

    stage(s1, As[1], Bs[1], ar, ac, br, bc);
    __syncthreads();
    do_mfma(As[1], Bs[1], wm, wn, l15, kr8, acc);

    // epilogue: C/D layout: col = lane&15, row = (lane>>4)*4 + reg
    float* outbase = qkvp + (size_t)ks * (3 * BD) + (size_t)w_idx * BD;
    #pragma unroll
    for (int fn = 0; fn < 2; ++fn) {
        const int col = nrow0 + wn * 32 + fn * 16 + l15;
        #pragma unroll
        for (int r = 0; r < 4; ++r) {
            const int row = m0 + wm * 16 + (lane >> 4) * 4 + r;
            outbase[(size_t)row * DIM + col] = acc[fn][r];
        }
    }
}

// ---------------------------------------------------------------------------
// K2: combine K-partials (float4), Taylor-moment attention, 128-wide grid
// barrier, BatchNorm tail on blocks 0..31.
// ---------------------------------------------------------------------------
__global__ __launch_bounds__(256) void attn_bn(
    const float* __restrict__ qkvp, const float* __restrict__ gamma,
    const float* __restrict__ beta, float* __restrict__ out0,
    float* __restrict__ out, int* __restrict__ sync)
{
    const int b = blockIdx.x;
    const int t = threadIdx.x;
    const size_t BD = (size_t)BATCH * DIM;
    const float inv_n = 0.03125f;  // 1/sqrt(1024)

    // combine split-K partials: thread t owns j = 4t .. 4t+3 (float4 loads)
    const int j0 = t * 4;
    float qv[4] = {0,0,0,0}, kn[4] = {0,0,0,0}, vv[4] = {0,0,0,0};
    #pragma unroll
    for (int p = 0; p < KSPLIT; ++p) {
        const float* base = qkvp + (size_t)p * 3 * BD + (size_t)b * DIM + j0;
        const float4 a = *(const float4*)base;
        const float4 k4 = *(const float4*)(base + BD);
        const float4 v4 = *(const float4*)(base + 2 * BD);
        qv[0] += a.x;  qv[1] += a.y;  qv[2] += a.z;  qv[3] += a.w;
        kn[0] += k4.x; kn[1] += k4.y; kn[2] += k4.z; kn[3] += k4.w;
        vv[0] += v4.x; vv[1] += v4.y; vv[2] += v4.z; vv[3] += v4.w;
    }
    #pragma unroll
    for (int e = 0; e < 4; ++e) kn[e] *= inv_n;

    float m0p[9], m1p[9];
    #pragma unroll
    for (int p = 0; p < 9; ++p) { m0p[p] = 0.f; m1p[p] = 0.f; }
    #pragma unroll
    for (int e = 0; e < 4; ++e) {
        float pw = 1.f;
        #pragma unroll
        for (int p = 0; p < 9; ++p) { m0p[p] += pw; m1p[p] += pw * vv[e]; pw *= kn[e]; }
    }
    #pragma unroll
    for (int p = 0; p < 9; ++p) {
        for (int off = 32; off; off >>= 1) {
            m0p[p] += __shfl_xor(m0p[p], off);
            m1p[p] += __shfl_xor(m1p[p], off);
        }
    }
    __shared__ float red0[4][9], red1[4][9];
    const int wvi = t >> 6, lane = t & 63;
    if (lane == 0) {
        #pragma unroll
        for (int p = 0; p < 9; ++p) { red0[wvi][p] = m0p[p]; red1[wvi][p] = m1p[p]; }
    }
    __syncthreads();

    const float invfact[9] = {1.f, 1.f, 0.5f, 1.f/6.f, 1.f/24.f, 1.f/120.f,
                              1.f/720.f, 1.f/5040.f, 1.f/40320.f};
    float c0[9], c1[9];
    #pragma unroll
    for (int p = 0; p < 9; ++p) {
        const float s0 = red0[0][p] + red0[1][p] + red0[2][p] + red0[3][p];
        const float s1 = red1[0][p] + red1[1][p] + red1[2][p] + red1[3][p];
        c0[p] = s0 * invfact[p];
        c1[p] = s1 * invfact[p];
    }
    float4 o4;
    float* op = (float*)&o4;
    #pragma unroll
    for (int e = 0; e < 4; ++e) {
        const float qi = qv[e];
        float S = c0[8], N = c1[8];
        #pragma unroll
        for (int p = 7; p >= 0; --p) { S = S * qi + c0[p]; N = N * qi + c1[p]; }
        op[e] = N / S + vv[e];
    }
    *(float4*)(out0 + (size_t)b * DIM + j0) = o4;

    // ---- grid barrier (128 blocks; proven) ----
    __syncthreads();   // drains vmcnt -> stores reached L2
    if (t == 0) __hip_atomic_fetch_add(sync, 1, __ATOMIC_RELEASE,
                                       __HIP_MEMORY_SCOPE_AGENT);
    if (b >= 32) return;
    if (t == 0) spin_until(sync, BATCH);
    __syncthreads();

    // ---- BatchNorm tail: block b handles features b*32 .. b*32+31 ----
    __shared__ float ls[8][32], ls2[8][32], la[32], lb[32];
    const int f = b * 32 + (t & 31);
    const int rc = t >> 5;  // 0..7, each covers 16 batch rows

    float x[16];
    float s = 0.f, s2 = 0.f;
    #pragma unroll
    for (int it = 0; it < 16; ++it) {
        const float xx = out0[(size_t)(rc * 16 + it) * DIM + f];
        x[it] = xx; s += xx; s2 += xx * xx;
    }
    ls[rc][t & 31] = s; ls2[rc][t & 31] = s2;
    __syncthreads();
    if (rc == 0) {
        float ss = 0.f, ss2 = 0.f;
        #pragma unroll
        for (int r = 0; r < 8; ++r) { ss += ls[r][t]; ss2 += ls2[r][t]; }
        const float mean = ss * (1.f / 128.f);
        const float var = ss2 * (1.f / 128.f) - mean * mean;  // biased
        const float inv = rsqrtf(var + EPS_BN);
        const float a = gamma[f] * inv;
        la[t] = a; lb[t] = beta[f] - mean * a;
    }
    __syncthreads();
    const float a = la[t & 31], bb = lb[t & 31];
    #pragma unroll
    for (int it = 0; it < 16; ++it) {
        out[(size_t)(rc * 16 + it) * DIM + f] = x[it] * a + bb;
    }
}

// ---------------------------------------------------------------------------
extern "C" void kernel_launch(void* const* d_in, const int* in_sizes, int n_in,
                              void* d_out, int out_size, void* d_ws, size_t ws_size,
                              hipStream_t stream)
{
    const float* z     = (const float*)d_in[0];
    const float* Wq    = (const float*)d_in[1];
    const float* Wk    = (const float*)d_in[2];
    const float* Wv    = (const float*)d_in[3];
    const float* gamma = (const float*)d_in[4];
    const float* beta  = (const float*)d_in[5];
    float* out = (float*)d_out;

    float* qkvp = (float*)d_ws;                              // 4 x 3 x 128 x 1024 f32
    float* out0 = qkvp + (size_t)KSPLIT * 3 * BATCH * DIM;   // 128 x 1024 f32
    int*   sync = (int*)(out0 + (size_t)BATCH * DIM);        // barrier counters

    qkv_gemm<<<4 * 48 * KSPLIT, 256, 0, stream>>>(z, Wq, Wk, Wv, qkvp, sync);
    attn_bn<<<BATCH, 256, 0, stream>>>(qkvp, gamma, beta, out0, out, sync);
}